// Round 9
// baseline (669.651 us; speedup 1.0000x reference)
//
#include <hip/hip_runtime.h>
#include <hip/hip_bf16.h>
#include <math.h>

#define N_NODES 50000
#define N_EDGES 600000
#define HDIM    128
#define NLAYERS 4
#define NGRAPH  256
#define SCAN_BLOCKS 196   // 196*256 = 50176 >= N_NODES

typedef _Float16 half8 __attribute__((ext_vector_type(8)));   // 8 x fp16 (4 VGPRs)
typedef __attribute__((ext_vector_type(4))) float float4v;    // MFMA acc
typedef unsigned short ushort_t;
typedef unsigned int uint_t;
typedef unsigned long long ulong_t;

__device__ __forceinline__ float h2f(ushort_t u) {
    union { ushort_t u; _Float16 h; } x; x.u = u; return (float)x.h;
}
__device__ __forceinline__ ushort_t f2h(float f) {
    union { ushort_t u; _Float16 h; } x; x.h = (_Float16)f; return x.u;
}

// ------------------------------------------------------------------
// LDS-tiled fp16 MFMA GEMM. Block = 128 rows x 64 cols, K=128 in one
// shot (no K-loop). 256 threads stage the 32KB A-tile into LDS
// (coalesced 16B chunks, +16B/row pad); each of 4 waves owns 32 rows,
// reads its 8 A-frags via ds_read_b128, preloads 16 B-frags from the
// L2-hot 64-col panel, runs 32 MFMAs, stores.
// Grid = (ceil(M/128), NC/64): thousands of short blocks -> TLP hides
// latency (vs the failed B-stationary persistent-wave structure).
// A source: Af32 (fp32, converted during staging) if non-null, else A16.
// mode 0 (embed, NC=128): write h f32 + h16 fp16
// mode 1 (layer, NC=512):
//   col<128 -> gr16 | 128..383 -> bigmid (gs,sv interleaved) | >=384 -> r16
// ------------------------------------------------------------------
__global__ __launch_bounds__(256) void gemm_lds(
    const ushort_t* __restrict__ A16, const float* __restrict__ Af32,
    const ushort_t* __restrict__ Bt,
    const float* __restrict__ bias, int M, int NC, int mode,
    float* __restrict__ hout, ushort_t* __restrict__ h16,
    ushort_t* __restrict__ gr16, ushort_t* __restrict__ bigmid,
    ushort_t* __restrict__ r16)
{
    __shared__ ushort_t As[128 * 136];   // 136 = 128 + 8 fp16 pad (272B row stride)

    const int tid  = threadIdx.x;
    const int wv   = tid >> 6, lane = tid & 63;
    const int quad = lane >> 4, l16 = lane & 15;
    const int row0    = blockIdx.x * 128;
    const int colbase = blockIdx.y * 64;

    // B fragments (all 4 waves use the same 64-col panel; L2-hot)
    half8 bf[4][4];
#pragma unroll
    for (int c = 0; c < 4; c++)
#pragma unroll
        for (int k0 = 0; k0 < 4; k0++)
            bf[c][k0] = *(const half8*)(Bt + (size_t)(colbase + c * 16 + l16) * 128
                                           + k0 * 32 + quad * 8);

    // Stage A tile: 128 rows x 256B = 2048 x 16B chunks, 8 per thread
#pragma unroll
    for (int i = 0; i < 8; i++) {
        int idx = i * 256 + tid;          // chunk index
        int r   = idx >> 4;               // tile row
        int c16 = idx & 15;               // 16B chunk within row
        int grow = row0 + r;
        if (grow >= M) grow = M - 1;      // clamp; stores guarded
        half8 v;
        if (Af32) {
            const float* ap = Af32 + (size_t)grow * 128 + c16 * 8;
            float4 f0 = *(const float4*)(ap);
            float4 f1 = *(const float4*)(ap + 4);
            v[0]=(_Float16)f0.x; v[1]=(_Float16)f0.y; v[2]=(_Float16)f0.z; v[3]=(_Float16)f0.w;
            v[4]=(_Float16)f1.x; v[5]=(_Float16)f1.y; v[6]=(_Float16)f1.z; v[7]=(_Float16)f1.w;
        } else {
            v = *(const half8*)(A16 + (size_t)grow * 128 + c16 * 8);
        }
        *(half8*)(As + r * 136 + c16 * 8) = v;
    }
    __syncthreads();

    // A fragments from LDS: wave wv owns rows [wv*32, wv*32+32)
    half8 a[2][4];
#pragma unroll
    for (int rf = 0; rf < 2; rf++)
#pragma unroll
        for (int k0 = 0; k0 < 4; k0++)
            a[rf][k0] = *(const half8*)(As + (wv * 32 + rf * 16 + l16) * 136
                                           + (k0 * 4 + quad) * 8);

    float4v acc[2][4];
    float4v z = {0.f, 0.f, 0.f, 0.f};
#pragma unroll
    for (int rf = 0; rf < 2; rf++)
#pragma unroll
        for (int c = 0; c < 4; c++) acc[rf][c] = z;

#pragma unroll
    for (int k0 = 0; k0 < 4; k0++)
#pragma unroll
        for (int rf = 0; rf < 2; rf++)
#pragma unroll
            for (int c = 0; c < 4; c++)
                acc[rf][c] = __builtin_amdgcn_mfma_f32_16x16x32_f16(
                    a[rf][k0], bf[c][k0], acc[rf][c], 0, 0, 0);

    // epilogue — C/D: col=lane&15, row=quad*4+reg
#pragma unroll
    for (int rf = 0; rf < 2; rf++)
#pragma unroll
        for (int c = 0; c < 4; c++) {
            const int col = colbase + c * 16 + l16;
            const float bv = bias[col];
#pragma unroll
            for (int r = 0; r < 4; r++) {
                const int row = row0 + wv * 32 + rf * 16 + quad * 4 + r;
                if (row < M) {
                    const float v = acc[rf][c][r] + bv;
                    if (mode == 0) {
                        hout[(size_t)row * 128 + col] = v;
                        h16[(size_t)row * 128 + col] = f2h(v);
                    } else {
                        if (col < 128)      gr16[(size_t)row * 128 + col] = f2h(v);
                        else if (col < 384) bigmid[(size_t)row * 256 + col - 128] = f2h(v);
                        else                r16[(size_t)row * 128 + col - 384] = f2h(v);
                    }
                }
            }
        }
}

// ------------------------------------------------------------------
// Weight panels (transposed, fp16). wembed_t[n][k] = W_embed[k][n]
// ------------------------------------------------------------------
__global__ void build_wembed(const float* __restrict__ W, ushort_t* __restrict__ Wt)
{
    int t = blockIdx.x * blockDim.x + threadIdx.x;   // t = n*128 + k
    if (t >= 128 * 128) return;
    int n = t >> 7, k = t & 127;
    Wt[t] = f2h(W[k * 128 + n]);
}

// wcat_t[l][p][k], physical column p:
//   p in [0,128)   : gr = Wg[l][k][p]            bias bg[l][p]
//   p in [128,384) : j=(p-128)>>1
//       even       : gs = Wg[l][128+k][j]        bias 0
//       odd        : sv = Ws[l][k][j]            bias bs[l][j]
//   p in [384,512) : r  = Wr[l][k][p-384]        bias br[l][p-384]
__global__ void build_wcat(const float* __restrict__ Wg, const float* __restrict__ Ws,
                           const float* __restrict__ Wr, const float* __restrict__ bg,
                           const float* __restrict__ bs, const float* __restrict__ br,
                           ushort_t* __restrict__ Wt, float* __restrict__ bcat)
{
    int t = blockIdx.x * blockDim.x + threadIdx.x;   // t = ((l*512)+p)*128 + k
    if (t >= NLAYERS * 512 * 128) return;
    int l = t >> 16;
    int r = t & 65535;
    int p = r >> 7;
    int k = r & 127;
    float v, b;
    if (p < 128)      { v = Wg[l * 32768 + k * 128 + p];            b = bg[l * 128 + p]; }
    else if (p < 384) {
        int j = (p - 128) >> 1;
        if (((p - 128) & 1) == 0) { v = Wg[l * 32768 + (128 + k) * 128 + j]; b = 0.f; }
        else                      { v = Ws[l * 16384 + k * 128 + j];         b = bs[l * 128 + j]; }
    }
    else              { v = Wr[l * 16384 + k * 128 + (p - 384)];    b = br[l * 128 + (p - 384)]; }
    Wt[t] = f2h(v);
    if (k == 0) bcat[l * 512 + p] = b;
}

// ------------------------------------------------------------------
// CSR build: histogram -> two-level scan -> scatter
// ------------------------------------------------------------------
__global__ __launch_bounds__(256) void hist_kernel(const int* __restrict__ ei,
                                                   int* __restrict__ cnt)
{
    int e = blockIdx.x * blockDim.x + threadIdx.x;
    if (e < N_EDGES) atomicAdd(&cnt[ei[N_EDGES + e]], 1);
}

__global__ __launch_bounds__(256) void scan_partial(const int* __restrict__ cnt,
                                                    int* __restrict__ part)
{
    __shared__ int ws[4];
    int tid = threadIdx.x, lane = tid & 63, wid = tid >> 6;
    int i = blockIdx.x * 256 + tid;
    int v = (i < N_NODES) ? cnt[i] : 0;
    int x = v;
#pragma unroll
    for (int ofs = 32; ofs > 0; ofs >>= 1) x += __shfl_down(x, ofs);
    if (lane == 0) ws[wid] = x;
    __syncthreads();
    if (tid == 0) part[blockIdx.x] = ws[0] + ws[1] + ws[2] + ws[3];
}

__global__ __launch_bounds__(256) void scan_root(const int* __restrict__ part,
                                                 int* __restrict__ partpre)
{
    __shared__ int ws[4];
    int tid = threadIdx.x, lane = tid & 63, wid = tid >> 6;
    int v = (tid < SCAN_BLOCKS) ? part[tid] : 0;
    int x = v;
#pragma unroll
    for (int ofs = 1; ofs < 64; ofs <<= 1) {
        int y = __shfl_up(x, ofs);
        if (lane >= ofs) x += y;
    }
    if (lane == 63) ws[wid] = x;
    __syncthreads();
    int add = 0;
    for (int w = 0; w < wid; w++) add += ws[w];
    if (tid < SCAN_BLOCKS) partpre[tid] = add + x - v;   // exclusive
}

__global__ __launch_bounds__(256) void scan_write(const int* __restrict__ cnt,
                                                  const int* __restrict__ partpre,
                                                  int* __restrict__ off)
{
    __shared__ int ws[4];
    int tid = threadIdx.x, lane = tid & 63, wid = tid >> 6;
    int i = blockIdx.x * 256 + tid;
    int v = (i < N_NODES) ? cnt[i] : 0;
    int x = v;
#pragma unroll
    for (int ofs = 1; ofs < 64; ofs <<= 1) {
        int y = __shfl_up(x, ofs);
        if (lane >= ofs) x += y;
    }
    if (lane == 63) ws[wid] = x;
    __syncthreads();
    int add = partpre[blockIdx.x];
    for (int w = 0; w < wid; w++) add += ws[w];
    if (i < N_NODES) off[i + 1] = add + x;
    if (i == 0) off[0] = 0;
}

__global__ __launch_bounds__(256) void scatter_kernel(const int* __restrict__ ei,
                                                      const int* __restrict__ off,
                                                      int* __restrict__ cur,
                                                      int* __restrict__ csr_send)
{
    int e = blockIdx.x * blockDim.x + threadIdx.x;
    if (e >= N_EDGES) return;
    int rec = ei[N_EDGES + e];
    int pos = off[rec] + atomicAdd(&cur[rec], 1);
    csr_send[pos] = ei[e];
}

// ------------------------------------------------------------------
// Node-centric aggregation + fused residual update (fp16 payloads).
// One WAVE per node; lane owns cols 2*lane, 2*lane+1 (one dwordx2/edge).
// 8-deep unroll for outstanding-load depth (avg degree 12).
// Fast gate: sv * rcp(1 + exp2(-(gr+gs)*log2e))
// ------------------------------------------------------------------
__device__ __forceinline__ float gate_msg(uint_t pk, float gr) {
    float gs = h2f((ushort_t)(pk & 0xffff));
    float sv = h2f((ushort_t)(pk >> 16));
    float e = __builtin_amdgcn_exp2f((gr + gs) * -1.44269504f);
    return sv * __builtin_amdgcn_rcpf(1.f + e);
}

__global__ __launch_bounds__(256) void agg_kernel(
    const int* __restrict__ off, const int* __restrict__ csr_send,
    const ushort_t* __restrict__ bigmid, const ushort_t* __restrict__ gr16,
    const ushort_t* __restrict__ r16, float* __restrict__ h,
    ushort_t* __restrict__ h16)
{
    const int wave = threadIdx.x >> 6, lane = threadIdx.x & 63;
    const int n = blockIdx.x * 4 + wave;
    if (n >= N_NODES) return;

    uint_t grp = *(const uint_t*)(gr16 + (size_t)n * 128 + 2 * lane);
    uint_t rp  = *(const uint_t*)(r16  + (size_t)n * 128 + 2 * lane);
    float gr0 = h2f((ushort_t)(grp & 0xffff)), gr1 = h2f((ushort_t)(grp >> 16));
    float acc0 = h2f((ushort_t)(rp & 0xffff)), acc1 = h2f((ushort_t)(rp >> 16));

    int p  = off[n];
    int p1 = off[n + 1];
    for (; p + 7 < p1; p += 8) {
        int s[8];
#pragma unroll
        for (int u = 0; u < 8; u++) s[u] = csr_send[p + u];
        ulong_t q[8];
#pragma unroll
        for (int u = 0; u < 8; u++)
            q[u] = *(const ulong_t*)(bigmid + (size_t)s[u] * 256 + 4 * lane);
#pragma unroll
        for (int u = 0; u < 8; u++) {
            acc0 += gate_msg((uint_t)q[u], gr0);
            acc1 += gate_msg((uint_t)(q[u] >> 32), gr1);
        }
    }
    for (; p + 1 < p1; p += 2) {
        int sa = csr_send[p], sb = csr_send[p + 1];
        ulong_t qa = *(const ulong_t*)(bigmid + (size_t)sa * 256 + 4 * lane);
        ulong_t qb = *(const ulong_t*)(bigmid + (size_t)sb * 256 + 4 * lane);
        acc0 += gate_msg((uint_t)qa, gr0); acc1 += gate_msg((uint_t)(qa >> 32), gr1);
        acc0 += gate_msg((uint_t)qb, gr0); acc1 += gate_msg((uint_t)(qb >> 32), gr1);
    }
    if (p < p1) {
        int sa = csr_send[p];
        ulong_t qa = *(const ulong_t*)(bigmid + (size_t)sa * 256 + 4 * lane);
        acc0 += gate_msg((uint_t)qa, gr0); acc1 += gate_msg((uint_t)(qa >> 32), gr1);
    }

    float2 hv = *(float2*)(h + (size_t)n * 128 + 2 * lane);
    hv.x += fmaxf(acc0, 0.f);
    hv.y += fmaxf(acc1, 0.f);
    *(float2*)(h + (size_t)n * 128 + 2 * lane) = hv;
    uint_t hp = (uint_t)f2h(hv.x) | ((uint_t)f2h(hv.y) << 16);
    *(uint_t*)(h16 + (size_t)n * 128 + 2 * lane) = hp;
}

// ------------------------------------------------------------------
// Pool: batch sorted -> contiguous range per graph.
// ------------------------------------------------------------------
__global__ __launch_bounds__(128) void pool_kernel(
    const float* __restrict__ h, const int* __restrict__ batch,
    float* __restrict__ hagg)
{
    int g = blockIdx.x;
    __shared__ int s_lo, s_hi;
    if (threadIdx.x == 0) {
        int lo = 0, hi = N_NODES;
        while (lo < hi) { int mid = (lo + hi) >> 1; if (batch[mid] < g) lo = mid + 1; else hi = mid; }
        s_lo = lo;
        hi = N_NODES;
        while (lo < hi) { int mid = (lo + hi) >> 1; if (batch[mid] < g + 1) lo = mid + 1; else hi = mid; }
        s_hi = lo;
    }
    __syncthreads();
    float acc = 0.f;
    int n = s_lo;
    for (; n + 3 < s_hi; n += 4)
        acc += (h[(size_t)n * 128 + threadIdx.x] + h[(size_t)(n + 1) * 128 + threadIdx.x])
             + (h[(size_t)(n + 2) * 128 + threadIdx.x] + h[(size_t)(n + 3) * 128 + threadIdx.x]);
    for (; n < s_hi; n++) acc += h[(size_t)n * 128 + threadIdx.x];
    hagg[(size_t)g * 128 + threadIdx.x] = acc;
}

// ------------------------------------------------------------------
// Head: out[g] = relu(hagg[g] @ W1 + b1) @ W2 + b2
// ------------------------------------------------------------------
__global__ __launch_bounds__(64) void head_kernel(
    const float* __restrict__ hagg, const float* __restrict__ W1,
    const float* __restrict__ b1, const float* __restrict__ W2,
    const float* __restrict__ b2, float* __restrict__ out)
{
    int g = blockIdx.x;
    int j = threadIdx.x;
    float acc = b1[j];
    for (int k = 0; k < 128; k++)
        acc += hagg[(size_t)g * 128 + k] * W1[k * 64 + j];
    float val = fmaxf(acc, 0.f) * W2[j];
#pragma unroll
    for (int off = 32; off > 0; off >>= 1)
        val += __shfl_down(val, off);
    if (j == 0) out[g] = val + b2[0];
}

// ------------------------------------------------------------------
extern "C" void kernel_launch(void* const* d_in, const int* in_sizes, int n_in,
                              void* d_out, int out_size, void* d_ws, size_t ws_size,
                              hipStream_t stream) {
    const float* h_in    = (const float*)d_in[0];
    const int*   ei      = (const int*)d_in[1];
    const int*   batch   = (const int*)d_in[2];
    const float* W_embed = (const float*)d_in[3];
    const float* b_embed = (const float*)d_in[4];
    const float* Wg      = (const float*)d_in[5];
    const float* bg      = (const float*)d_in[6];
    const float* Ws      = (const float*)d_in[7];
    const float* bs      = (const float*)d_in[8];
    const float* Wr      = (const float*)d_in[9];
    const float* br      = (const float*)d_in[10];
    const float* W1      = (const float*)d_in[11];
    const float* b1      = (const float*)d_in[12];
    const float* W2      = (const float*)d_in[13];
    const float* b2      = (const float*)d_in[14];
    float* out = (float*)d_out;

    // workspace layout (fp32 first, then fp16, then ints)
    float* ws = (float*)d_ws;
    float*    h     = ws;                                    // N*128 f32
    float*    hagg  = h + (size_t)N_NODES * 128;             // G*128 f32
    float*    bcat  = hagg + NGRAPH * 128;                   // 4*512 f32
    ushort_t* h16   = (ushort_t*)(bcat + NLAYERS * 512);     // N*128 fp16
    ushort_t* gr16  = h16 + (size_t)N_NODES * 128;           // N*128
    ushort_t* r16   = gr16 + (size_t)N_NODES * 128;          // N*128
    ushort_t* bigmid= r16 + (size_t)N_NODES * 128;           // N*256 fp16
    ushort_t* wet   = bigmid + (size_t)N_NODES * 256;        // 128*128
    ushort_t* wct   = wet + 128 * 128;                       // 4*512*128
    int* cnt      = (int*)(wct + NLAYERS * 512 * 128);       // N
    int* cur      = cnt + N_NODES;                           // N
    int* off      = cur + N_NODES;                           // N+1
    int* csr_send = off + N_NODES + 1;                       // E
    int* part     = csr_send + N_EDGES;                      // SCAN_BLOCKS
    int* partpre  = part + SCAN_BLOCKS;                      // SCAN_BLOCKS

    // CSR build
    hipMemsetAsync(cnt, 0, (size_t)2 * N_NODES * sizeof(int), stream);
    hist_kernel<<<(N_EDGES + 255) / 256, 256, 0, stream>>>(ei, cnt);
    scan_partial<<<SCAN_BLOCKS, 256, 0, stream>>>(cnt, part);
    scan_root<<<1, 256, 0, stream>>>(part, partpre);
    scan_write<<<SCAN_BLOCKS, 256, 0, stream>>>(cnt, partpre, off);
    scatter_kernel<<<(N_EDGES + 255) / 256, 256, 0, stream>>>(ei, off, cur, csr_send);

    // weight panels
    build_wembed<<<(128 * 128 + 255) / 256, 256, 0, stream>>>(W_embed, wet);
    build_wcat<<<(NLAYERS * 512 * 128 + 255) / 256, 256, 0, stream>>>(
        Wg, Ws, Wr, bg, bs, br, wct, bcat);

    const int rtiles = (N_NODES + 127) / 128;   // 391

    // embed: h = h_in @ W_embed + b_embed  (fp32 A converted during staging)
    {
        dim3 grid(rtiles, 2);
        gemm_lds<<<grid, 256, 0, stream>>>(nullptr, h_in, wet, b_embed,
                                           N_NODES, 128, 0,
                                           h, h16, nullptr, nullptr, nullptr);
    }

    for (int l = 0; l < NLAYERS; l++) {
        dim3 grid(rtiles, 8);
        gemm_lds<<<grid, 256, 0, stream>>>(h16, nullptr,
                                           wct + (size_t)l * 512 * 128,
                                           bcat + l * 512, N_NODES, 512, 1,
                                           nullptr, nullptr, gr16, bigmid, r16);
        agg_kernel<<<(N_NODES + 3) / 4, 256, 0, stream>>>(off, csr_send, bigmid,
                                                          gr16, r16, h, h16);
    }

    pool_kernel<<<NGRAPH, 128, 0, stream>>>(h, batch, hagg);
    head_kernel<<<NGRAPH, 64, 0, stream>>>(hagg, W1, b1, W2, b2, out);
}

// Round 10
// 562.210 us; speedup vs baseline: 1.1911x; 1.1911x over previous
//
#include <hip/hip_runtime.h>
#include <hip/hip_bf16.h>
#include <math.h>

#define N_NODES 50000
#define N_EDGES 600000
#define HDIM    128
#define NLAYERS 4
#define NGRAPH  256
#define SCAN_BLOCKS 196   // 196*256 = 50176 >= N_NODES

typedef _Float16 half8 __attribute__((ext_vector_type(8)));   // 8 x fp16 (4 VGPRs)
typedef __attribute__((ext_vector_type(4))) float float4v;    // MFMA acc
typedef unsigned short ushort_t;
typedef unsigned int uint_t;
typedef unsigned long long ulong_t;

__device__ __forceinline__ float h2f(ushort_t u) {
    union { ushort_t u; _Float16 h; } x; x.u = u; return (float)x.h;
}
__device__ __forceinline__ ushort_t f2h(float f) {
    union { ushort_t u; _Float16 h; } x; x.h = (_Float16)f; return x.u;
}

// ------------------------------------------------------------------
// fp16 MFMA GEMM, B-stationary, A register-double-buffered. No LDS.
// (R5 champion structure: 64 cols/wave, 16-row tiles, grid 384x2.)
// C[M x NC] = A @ B + bias ; Bt is [NC x 128] fp16 (k-contiguous rows).
// Wave preloads 16 B-frags once, grid-strides over 16-row A tiles
// with next-tile prefetch.
// A source: Af32 (fp32, converted in-register) if non-null, else A16.
// mode 0 (embed, NC=128): write h f32 + h16 fp16
// mode 1 (layer, NC=512), physical col p:
//   p<128        -> grr[row*256 + 2*p]          (gr)
//   128<=p<384   -> bigmid[row*256 + p-128]     (gs,sv interleaved)
//   p>=384       -> grr[row*256 + 2*(p-384)+1]  (r)
// ------------------------------------------------------------------
__global__ __launch_bounds__(256) void mfma_gemm_f16(
    const ushort_t* __restrict__ A16, const float* __restrict__ Af32,
    const ushort_t* __restrict__ Bt,
    const float* __restrict__ bias, int M, int mode,
    float* __restrict__ hout, ushort_t* __restrict__ h16,
    ushort_t* __restrict__ grr, ushort_t* __restrict__ bigmid)
{
    const int tid  = threadIdx.x;
    const int wave = tid >> 6, lane = tid & 63;
    const int quad = lane >> 4, l16 = lane & 15;
    const int nwaves = blockDim.x >> 6;
    const int colbase = (blockIdx.y * nwaves + wave) * 64;   // 64 cols per wave

    // B fragments: resident for the whole kernel (16 x 16B loads)
    half8 bf[4][4];
#pragma unroll
    for (int c = 0; c < 4; c++)
#pragma unroll
        for (int k0 = 0; k0 < 4; k0++)
            bf[c][k0] = *(const half8*)(Bt + (size_t)(colbase + c * 16 + l16) * 128
                                           + k0 * 32 + quad * 8);

    const int ntiles = (M + 15) >> 4;
    int tile = blockIdx.x;
    if (tile >= ntiles) return;

    half8 acur[4], anext[4];
    {
        int arow = tile * 16 + l16;
        if (arow >= M) arow = M - 1;
        if (Af32) {
            const float* ap = Af32 + (size_t)arow * 128 + quad * 8;
#pragma unroll
            for (int k0 = 0; k0 < 4; k0++) {
                float4 f0 = *(const float4*)(ap + k0 * 32);
                float4 f1 = *(const float4*)(ap + k0 * 32 + 4);
                half8 a;
                a[0]=(_Float16)f0.x; a[1]=(_Float16)f0.y; a[2]=(_Float16)f0.z; a[3]=(_Float16)f0.w;
                a[4]=(_Float16)f1.x; a[5]=(_Float16)f1.y; a[6]=(_Float16)f1.z; a[7]=(_Float16)f1.w;
                acur[k0] = a;
            }
        } else {
            const ushort_t* ap = A16 + (size_t)arow * 128 + quad * 8;
#pragma unroll
            for (int k0 = 0; k0 < 4; k0++) acur[k0] = *(const half8*)(ap + k0 * 32);
        }
    }

    while (true) {
        const int nt = tile + gridDim.x;
        const bool have_next = nt < ntiles;
        if (have_next) {
            int arow = nt * 16 + l16;
            if (arow >= M) arow = M - 1;
            if (Af32) {
                const float* ap = Af32 + (size_t)arow * 128 + quad * 8;
#pragma unroll
                for (int k0 = 0; k0 < 4; k0++) {
                    float4 f0 = *(const float4*)(ap + k0 * 32);
                    float4 f1 = *(const float4*)(ap + k0 * 32 + 4);
                    half8 a;
                    a[0]=(_Float16)f0.x; a[1]=(_Float16)f0.y; a[2]=(_Float16)f0.z; a[3]=(_Float16)f0.w;
                    a[4]=(_Float16)f1.x; a[5]=(_Float16)f1.y; a[6]=(_Float16)f1.z; a[7]=(_Float16)f1.w;
                    anext[k0] = a;
                }
            } else {
                const ushort_t* ap = A16 + (size_t)arow * 128 + quad * 8;
#pragma unroll
                for (int k0 = 0; k0 < 4; k0++) anext[k0] = *(const half8*)(ap + k0 * 32);
            }
        }

        float4v acc[4];
        float4v z = {0.f, 0.f, 0.f, 0.f};
#pragma unroll
        for (int c = 0; c < 4; c++) acc[c] = z;
#pragma unroll
        for (int k0 = 0; k0 < 4; k0++)
#pragma unroll
            for (int c = 0; c < 4; c++)
                acc[c] = __builtin_amdgcn_mfma_f32_16x16x32_f16(acur[k0], bf[c][k0], acc[c], 0, 0, 0);

        // epilogue — C/D: col=lane&15, row=quad*4+reg
#pragma unroll
        for (int c = 0; c < 4; c++) {
            const int col = colbase + c * 16 + l16;
            const float bv = bias[col];
#pragma unroll
            for (int r = 0; r < 4; r++) {
                const int row = tile * 16 + quad * 4 + r;
                if (row < M) {
                    const float v = acc[c][r] + bv;
                    if (mode == 0) {
                        hout[(size_t)row * 128 + col] = v;
                        h16[(size_t)row * 128 + col] = f2h(v);
                    } else {
                        if (col < 128)      grr[(size_t)row * 256 + 2 * col] = f2h(v);
                        else if (col < 384) bigmid[(size_t)row * 256 + col - 128] = f2h(v);
                        else                grr[(size_t)row * 256 + 2 * (col - 384) + 1] = f2h(v);
                    }
                }
            }
        }

        if (!have_next) break;
#pragma unroll
        for (int k0 = 0; k0 < 4; k0++) acur[k0] = anext[k0];
        tile = nt;
    }
}

// ------------------------------------------------------------------
// Weight panels (transposed, fp16). wembed_t[n][k] = W_embed[k][n]
// ------------------------------------------------------------------
__global__ void build_wembed(const float* __restrict__ W, ushort_t* __restrict__ Wt)
{
    int t = blockIdx.x * blockDim.x + threadIdx.x;   // t = n*128 + k
    if (t >= 128 * 128) return;
    int n = t >> 7, k = t & 127;
    Wt[t] = f2h(W[k * 128 + n]);
}

// wcat_t[l][p][k], physical column p:
//   p in [0,128)   : gr = Wg[l][k][p]            bias bg[l][p]
//   p in [128,384) : j=(p-128)>>1
//       even       : gs = Wg[l][128+k][j]        bias 0
//       odd        : sv = Ws[l][k][j]            bias bs[l][j]
//   p in [384,512) : r  = Wr[l][k][p-384]        bias br[l][p-384]
__global__ void build_wcat(const float* __restrict__ Wg, const float* __restrict__ Ws,
                           const float* __restrict__ Wr, const float* __restrict__ bg,
                           const float* __restrict__ bs, const float* __restrict__ br,
                           ushort_t* __restrict__ Wt, float* __restrict__ bcat)
{
    int t = blockIdx.x * blockDim.x + threadIdx.x;   // t = ((l*512)+p)*128 + k
    if (t >= NLAYERS * 512 * 128) return;
    int l = t >> 16;
    int r = t & 65535;
    int p = r >> 7;
    int k = r & 127;
    float v, b;
    if (p < 128)      { v = Wg[l * 32768 + k * 128 + p];            b = bg[l * 128 + p]; }
    else if (p < 384) {
        int j = (p - 128) >> 1;
        if (((p - 128) & 1) == 0) { v = Wg[l * 32768 + (128 + k) * 128 + j]; b = 0.f; }
        else                      { v = Ws[l * 16384 + k * 128 + j];         b = bs[l * 128 + j]; }
    }
    else              { v = Wr[l * 16384 + k * 128 + (p - 384)];    b = br[l * 128 + (p - 384)]; }
    Wt[t] = f2h(v);
    if (k == 0) bcat[l * 512 + p] = b;
}

// ------------------------------------------------------------------
// CSR build: histogram -> two-level scan -> scatter
// ------------------------------------------------------------------
__global__ __launch_bounds__(256) void hist_kernel(const int* __restrict__ ei,
                                                   int* __restrict__ cnt)
{
    int e = blockIdx.x * blockDim.x + threadIdx.x;
    if (e < N_EDGES) atomicAdd(&cnt[ei[N_EDGES + e]], 1);
}

__global__ __launch_bounds__(256) void scan_partial(const int* __restrict__ cnt,
                                                    int* __restrict__ part)
{
    __shared__ int ws[4];
    int tid = threadIdx.x, lane = tid & 63, wid = tid >> 6;
    int i = blockIdx.x * 256 + tid;
    int v = (i < N_NODES) ? cnt[i] : 0;
    int x = v;
#pragma unroll
    for (int ofs = 32; ofs > 0; ofs >>= 1) x += __shfl_down(x, ofs);
    if (lane == 0) ws[wid] = x;
    __syncthreads();
    if (tid == 0) part[blockIdx.x] = ws[0] + ws[1] + ws[2] + ws[3];
}

__global__ __launch_bounds__(256) void scan_root(const int* __restrict__ part,
                                                 int* __restrict__ partpre)
{
    __shared__ int ws[4];
    int tid = threadIdx.x, lane = tid & 63, wid = tid >> 6;
    int v = (tid < SCAN_BLOCKS) ? part[tid] : 0;
    int x = v;
#pragma unroll
    for (int ofs = 1; ofs < 64; ofs <<= 1) {
        int y = __shfl_up(x, ofs);
        if (lane >= ofs) x += y;
    }
    if (lane == 63) ws[wid] = x;
    __syncthreads();
    int add = 0;
    for (int w = 0; w < wid; w++) add += ws[w];
    if (tid < SCAN_BLOCKS) partpre[tid] = add + x - v;   // exclusive
}

__global__ __launch_bounds__(256) void scan_write(const int* __restrict__ cnt,
                                                  const int* __restrict__ partpre,
                                                  int* __restrict__ off)
{
    __shared__ int ws[4];
    int tid = threadIdx.x, lane = tid & 63, wid = tid >> 6;
    int i = blockIdx.x * 256 + tid;
    int v = (i < N_NODES) ? cnt[i] : 0;
    int x = v;
#pragma unroll
    for (int ofs = 1; ofs < 64; ofs <<= 1) {
        int y = __shfl_up(x, ofs);
        if (lane >= ofs) x += y;
    }
    if (lane == 63) ws[wid] = x;
    __syncthreads();
    int add = partpre[blockIdx.x];
    for (int w = 0; w < wid; w++) add += ws[w];
    if (i < N_NODES) off[i + 1] = add + x;
    if (i == 0) off[0] = 0;
}

__global__ __launch_bounds__(256) void scatter_kernel(const int* __restrict__ ei,
                                                      const int* __restrict__ off,
                                                      int* __restrict__ cur,
                                                      int* __restrict__ csr_send)
{
    int e = blockIdx.x * blockDim.x + threadIdx.x;
    if (e >= N_EDGES) return;
    int rec = ei[N_EDGES + e];
    int pos = off[rec] + atomicAdd(&cur[rec], 1);
    csr_send[pos] = ei[e];
}

// ------------------------------------------------------------------
// Node-centric aggregation + fused residual update (fp16 payloads).
// One WAVE per node; lane owns cols 2*lane, 2*lane+1.
// Seed: one 8B load from grr = (gr0,r0,gr1,r1).
// Per edge: one dwordx2 gather from bigmid = (gs0,sv0,gs1,sv1).
// Fast gate: sv * rcp(1 + exp2(-(gr+gs)*log2e))
// ------------------------------------------------------------------
__device__ __forceinline__ float gate_msg(uint_t pk, float gr) {
    float gs = h2f((ushort_t)(pk & 0xffff));
    float sv = h2f((ushort_t)(pk >> 16));
    float e = __builtin_amdgcn_exp2f((gr + gs) * -1.44269504f);
    return sv * __builtin_amdgcn_rcpf(1.f + e);
}

__global__ __launch_bounds__(256) void agg_kernel(
    const int* __restrict__ off, const int* __restrict__ csr_send,
    const ushort_t* __restrict__ bigmid, const ushort_t* __restrict__ grr,
    float* __restrict__ h, ushort_t* __restrict__ h16)
{
    const int wave = threadIdx.x >> 6, lane = threadIdx.x & 63;
    const int n = blockIdx.x * 4 + wave;
    if (n >= N_NODES) return;

    ulong_t seed = *(const ulong_t*)(grr + (size_t)n * 256 + 4 * lane);
    float gr0  = h2f((ushort_t)(seed & 0xffff));
    float acc0 = h2f((ushort_t)((seed >> 16) & 0xffff));
    float gr1  = h2f((ushort_t)((seed >> 32) & 0xffff));
    float acc1 = h2f((ushort_t)(seed >> 48));

    int p  = off[n];
    int p1 = off[n + 1];
    for (; p + 7 < p1; p += 8) {
        int s[8];
#pragma unroll
        for (int u = 0; u < 8; u++) s[u] = csr_send[p + u];
        ulong_t q[8];
#pragma unroll
        for (int u = 0; u < 8; u++)
            q[u] = *(const ulong_t*)(bigmid + (size_t)s[u] * 256 + 4 * lane);
#pragma unroll
        for (int u = 0; u < 8; u++) {
            acc0 += gate_msg((uint_t)q[u], gr0);
            acc1 += gate_msg((uint_t)(q[u] >> 32), gr1);
        }
    }
    for (; p + 1 < p1; p += 2) {
        int sa = csr_send[p], sb = csr_send[p + 1];
        ulong_t qa = *(const ulong_t*)(bigmid + (size_t)sa * 256 + 4 * lane);
        ulong_t qb = *(const ulong_t*)(bigmid + (size_t)sb * 256 + 4 * lane);
        acc0 += gate_msg((uint_t)qa, gr0); acc1 += gate_msg((uint_t)(qa >> 32), gr1);
        acc0 += gate_msg((uint_t)qb, gr0); acc1 += gate_msg((uint_t)(qb >> 32), gr1);
    }
    if (p < p1) {
        int sa = csr_send[p];
        ulong_t qa = *(const ulong_t*)(bigmid + (size_t)sa * 256 + 4 * lane);
        acc0 += gate_msg((uint_t)qa, gr0); acc1 += gate_msg((uint_t)(qa >> 32), gr1);
    }

    float2 hv = *(float2*)(h + (size_t)n * 128 + 2 * lane);
    hv.x += fmaxf(acc0, 0.f);
    hv.y += fmaxf(acc1, 0.f);
    *(float2*)(h + (size_t)n * 128 + 2 * lane) = hv;
    uint_t hp = (uint_t)f2h(hv.x) | ((uint_t)f2h(hv.y) << 16);
    *(uint_t*)(h16 + (size_t)n * 128 + 2 * lane) = hp;
}

// ------------------------------------------------------------------
// Pool (segmented): batch is sorted. Each block reduces a 64-node
// chunk; one fp32 atomicAdd per (segment boundary, column).
// ------------------------------------------------------------------
__global__ __launch_bounds__(128) void pool_kernel(
    const float* __restrict__ h, const int* __restrict__ batch,
    float* __restrict__ hagg)
{
    const int j  = threadIdx.x;
    const int n0 = blockIdx.x * 64;
    int n1 = n0 + 64;
    if (n1 > N_NODES) n1 = N_NODES;
    if (n0 >= N_NODES) return;

    int g_cur = batch[n0];
    float acc = 0.f;
    for (int n = n0; n < n1; n++) {
        int g = batch[n];
        if (g != g_cur) {
            unsafeAtomicAdd(&hagg[(size_t)g_cur * 128 + j], acc);
            acc = 0.f;
            g_cur = g;
        }
        acc += h[(size_t)n * 128 + j];
    }
    unsafeAtomicAdd(&hagg[(size_t)g_cur * 128 + j], acc);
}

// ------------------------------------------------------------------
// Head: out[g] = relu(hagg[g] @ W1 + b1) @ W2 + b2
// ------------------------------------------------------------------
__global__ __launch_bounds__(64) void head_kernel(
    const float* __restrict__ hagg, const float* __restrict__ W1,
    const float* __restrict__ b1, const float* __restrict__ W2,
    const float* __restrict__ b2, float* __restrict__ out)
{
    int g = blockIdx.x;
    int j = threadIdx.x;
    float acc = b1[j];
    for (int k = 0; k < 128; k++)
        acc += hagg[(size_t)g * 128 + k] * W1[k * 64 + j];
    float val = fmaxf(acc, 0.f) * W2[j];
#pragma unroll
    for (int off = 32; off > 0; off >>= 1)
        val += __shfl_down(val, off);
    if (j == 0) out[g] = val + b2[0];
}

// ------------------------------------------------------------------
extern "C" void kernel_launch(void* const* d_in, const int* in_sizes, int n_in,
                              void* d_out, int out_size, void* d_ws, size_t ws_size,
                              hipStream_t stream) {
    const float* h_in    = (const float*)d_in[0];
    const int*   ei      = (const int*)d_in[1];
    const int*   batch   = (const int*)d_in[2];
    const float* W_embed = (const float*)d_in[3];
    const float* b_embed = (const float*)d_in[4];
    const float* Wg      = (const float*)d_in[5];
    const float* bg      = (const float*)d_in[6];
    const float* Ws      = (const float*)d_in[7];
    const float* bs      = (const float*)d_in[8];
    const float* Wr      = (const float*)d_in[9];
    const float* br      = (const float*)d_in[10];
    const float* W1      = (const float*)d_in[11];
    const float* b1      = (const float*)d_in[12];
    const float* W2      = (const float*)d_in[13];
    const float* b2      = (const float*)d_in[14];
    float* out = (float*)d_out;

    // workspace layout (fp32 first, then fp16, then ints)
    float* ws = (float*)d_ws;
    float*    h     = ws;                                    // N*128 f32
    float*    hagg  = h + (size_t)N_NODES * 128;             // G*128 f32
    float*    bcat  = hagg + NGRAPH * 128;                   // 4*512 f32
    ushort_t* h16   = (ushort_t*)(bcat + NLAYERS * 512);     // N*128 fp16
    ushort_t* grr   = h16 + (size_t)N_NODES * 128;           // N*256 fp16 (gr,r pairs)
    ushort_t* bigmid= grr + (size_t)N_NODES * 256;           // N*256 fp16
    ushort_t* wet   = bigmid + (size_t)N_NODES * 256;        // 128*128
    ushort_t* wct   = wet + 128 * 128;                       // 4*512*128
    int* cnt      = (int*)(wct + NLAYERS * 512 * 128);       // N
    int* cur      = cnt + N_NODES;                           // N
    int* off      = cur + N_NODES;                           // N+1
    int* csr_send = off + N_NODES + 1;                       // E
    int* part     = csr_send + N_EDGES;                      // SCAN_BLOCKS
    int* partpre  = part + SCAN_BLOCKS;                      // SCAN_BLOCKS

    // CSR build
    hipMemsetAsync(cnt, 0, (size_t)2 * N_NODES * sizeof(int), stream);
    hist_kernel<<<(N_EDGES + 255) / 256, 256, 0, stream>>>(ei, cnt);
    scan_partial<<<SCAN_BLOCKS, 256, 0, stream>>>(cnt, part);
    scan_root<<<1, 256, 0, stream>>>(part, partpre);
    scan_write<<<SCAN_BLOCKS, 256, 0, stream>>>(cnt, partpre, off);
    scatter_kernel<<<(N_EDGES + 255) / 256, 256, 0, stream>>>(ei, off, cur, csr_send);

    // weight panels
    build_wembed<<<(128 * 128 + 255) / 256, 256, 0, stream>>>(W_embed, wet);
    build_wcat<<<(NLAYERS * 512 * 128 + 255) / 256, 256, 0, stream>>>(
        Wg, Ws, Wr, bg, bs, br, wct, bcat);

    // embed: h = h_in @ W_embed + b_embed  (reads fp32 A directly)
    {
        dim3 grid(768, 1);
        mfma_gemm_f16<<<grid, 128, 0, stream>>>(nullptr, h_in, wet, b_embed,
                                                N_NODES, 0, h, h16,
                                                nullptr, nullptr);
    }

    for (int l = 0; l < NLAYERS; l++) {
        dim3 grid(384, 2);
        mfma_gemm_f16<<<grid, 256, 0, stream>>>(h16, nullptr,
                                                wct + (size_t)l * 512 * 128,
                                                bcat + l * 512, N_NODES, 1,
                                                nullptr, nullptr, grr, bigmid);
        agg_kernel<<<(N_NODES + 3) / 4, 256, 0, stream>>>(off, csr_send, bigmid,
                                                          grr, h, h16);
    }

    hipMemsetAsync(hagg, 0, (size_t)NGRAPH * 128 * sizeof(float), stream);
    pool_kernel<<<(N_NODES + 63) / 64, 128, 0, stream>>>(h, batch, hagg);
    head_kernel<<<NGRAPH, 64, 0, stream>>>(hagg, W1, b1, W2, b2, out);
}